// Round 5
// baseline (332.301 us; speedup 1.0000x reference)
//
#include <hip/hip_runtime.h>

#define BATCH 2048

// block-wide f32 sum; all threads get the result. red >= 32 floats.
__device__ __forceinline__ float blockReduceSumF(float v, float* red, int tid, int nwaves) {
  #pragma unroll
  for (int off = 32; off > 0; off >>= 1) v += __shfl_xor(v, off);
  __syncthreads();
  if ((tid & 63) == 0) red[tid >> 6] = v;
  __syncthreads();
  if (tid == 0) {
    float s = red[0];
    for (int i = 1; i < nwaves; i++) s += red[i];
    red[31] = s;
  }
  __syncthreads();
  return red[31];
}

// packed 2-value block reduce (one barrier sequence); per-component order identical
// to two sequential blockReduceSumF calls -> bit-exact. red >= 32 floats; nwaves <= 8.
__device__ __forceinline__ float2 blockReduceSum2F(float a, float b, float* red, int tid, int nwaves) {
  #pragma unroll
  for (int off = 32; off > 0; off >>= 1) { a += __shfl_xor(a, off); b += __shfl_xor(b, off); }
  __syncthreads();
  if ((tid & 63) == 0) { red[tid >> 6] = a; red[(tid >> 6) + 16] = b; }
  __syncthreads();
  if (tid == 0) {
    float sa = red[0], sb = red[16];
    for (int i = 1; i < nwaves; i++) { sa += red[i]; sb += red[16 + i]; }
    red[30] = sa; red[31] = sb;
  }
  __syncthreads();
  return make_float2(red[30], red[31]);
}

// 4-wave (256-thread) group reduce; seg = 4-float LDS segment for this group.
__device__ __forceinline__ float groupReduce4w(float v, float* seg, int tj) {
  #pragma unroll
  for (int off = 32; off > 0; off >>= 1) v += __shfl_xor(v, off);
  __syncthreads();
  if ((tj & 63) == 0) seg[tj >> 6] = v;
  __syncthreads();
  return (seg[0] + seg[1]) + (seg[2] + seg[3]);
}

// R19: bit-exact emulation of the old 256-thread blockReduceSumF on 128 threads.
// Thread tid = c2*2 + h holds the partials of old lanes q=2h (a0) and q=2h+1 (a1)
// (old tid_old = c2*4 + q). New lane = (c2&31)*2 + h, so old-lane c2 bit k lives at
// new lane bit k+1 and old q-bit1 (=h) at bit 0. Old butterfly offsets 32,16,8,4
// (c2 bits 3..0) -> new shfl_xor 16,8,4,2; old offset 2 (q bit1) -> new offset 1;
// old offset 1 (q bit0) -> in-thread add (FP add bitwise-commutative). Old-wave w
// covered c2 16w..16w+15 -> new lane groups {wave, lane<32}: sums land on lanes 0/32
// of each new wave -> red[0..3], combined in the old sequential order.
__device__ __forceinline__ float emulR128(float a0, float a1, float* red, int tid) {
  #pragma unroll
  for (int off = 16; off >= 2; off >>= 1) { a0 += __shfl_xor(a0, off); a1 += __shfl_xor(a1, off); }
  a0 += __shfl_xor(a0, 1);
  a1 += __shfl_xor(a1, 1);
  float w = a0 + a1;
  __syncthreads();
  if ((tid & 31) == 0) red[tid >> 5] = w;
  __syncthreads();
  return ((red[0] + red[1]) + red[2]) + red[3];
}

// ---------------- K0a: pack conv2 weights -> w2t2[cc][c2][28] (229 KB) ----------------
__global__ void k0_w2t(const float* __restrict__ w2, float* __restrict__ w2t2) {
  int i = blockIdx.x * 256 + threadIdx.x;  // over 57344
  if (i >= 57344) return;
  int cc = i / 1792;
  int r = i - cc * 1792;
  int c2 = r / 28;
  int k = r - c2 * 28;
  w2t2[i] = (k < 25) ? w2[c2 * 800 + cc * 25 + k] : 0.0f;
}

// ---------------- K1: conv1 + ternarize -> sign map + alpha1 (f32) ----------------
// (512,4): VGPR cap 128, 2 blocks/CU — no spill (R16 fix, confirmed R2).
__global__ __launch_bounds__(512, 4) void k1_conv1(
    const float* __restrict__ x, const float* __restrict__ w1, const float* __restrict__ b1,
    signed char* __restrict__ s1full, float* __restrict__ alpha1) {
  __shared__ float xs[784];
  __shared__ float wsm[800];
  __shared__ float red[32];

  const int tid = threadIdx.x;
  const int smp = blockIdx.x;

  for (int j = tid; j < 784; j += 512) xs[j] = x[smp * 784 + j];
  for (int j = tid; j < 800; j += 512) wsm[j] = w1[j];
  __syncthreads();

  const int c = tid >> 4;
  const int g = tid & 15;
  const float bias = b1[c];
  const float* wc = &wsm[c * 25];

  float a[36];
  float asum = 0.0f;
  #pragma unroll
  for (int tt = 0; tt < 3; tt++) {
    const int t = g + (tt << 4);
    const int r = t >> 1;
    const int hx = (t & 1) * 12;
    float acc[12];
    #pragma unroll
    for (int i = 0; i < 12; i++) acc[i] = bias;
    #pragma unroll
    for (int ky = 0; ky < 5; ky++) {
      const float* xp = &xs[(r + ky) * 28 + hx];
      float xrow[16];
      *(float4*)&xrow[0]  = *(const float4*)&xp[0];
      *(float4*)&xrow[4]  = *(const float4*)&xp[4];
      *(float4*)&xrow[8]  = *(const float4*)&xp[8];
      *(float4*)&xrow[12] = *(const float4*)&xp[12];
      #pragma unroll
      for (int kx = 0; kx < 5; kx++) {
        const float w = wc[ky * 5 + kx];
        #pragma unroll
        for (int i = 0; i < 12; i++) acc[i] = fmaf(xrow[i + kx], w, acc[i]);
      }
    }
    #pragma unroll
    for (int i = 0; i < 12; i++) { a[tt * 12 + i] = acc[i]; asum += fabsf(acc[i]); }
  }

  float tot = blockReduceSumF(asum, red, tid, 8);
  float delta = (0.7f * tot) / 18432.0f;

  float msum = 0.0f, mcnt = 0.0f;
  #pragma unroll
  for (int i = 0; i < 36; i++) {
    float fa = fabsf(a[i]);
    if (fa > delta) { msum += fa; mcnt += 1.0f; }
  }
  float2 mm = blockReduceSum2F(msum, mcnt, red, tid, 8);
  if (tid == 0) alpha1[smp] = (mm.y > 0.0f) ? (mm.x / mm.y) : 0.0f;

  // packed sign stores: 12 bytes -> 3 dwords per tt.
  signed char* sp = s1full + (size_t)smp * 18432 + c * 576 + g * 12;
  #pragma unroll
  for (int tt = 0; tt < 3; tt++) {
    int s_[12];
    #pragma unroll
    for (int i = 0; i < 12; i++) {
      float v = a[tt * 12 + i];
      s_[i] = (v > delta) ? 1 : ((v < -delta) ? -1 : 0);
    }
    unsigned u0 = (s_[0] & 0xFF) | ((s_[1] & 0xFF) << 8) | ((s_[2] & 0xFF) << 16) |
                  (((unsigned)(s_[3] & 0xFF)) << 24);
    unsigned u1 = (s_[4] & 0xFF) | ((s_[5] & 0xFF) << 8) | ((s_[6] & 0xFF) << 16) |
                  (((unsigned)(s_[7] & 0xFF)) << 24);
    unsigned u2 = (s_[8] & 0xFF) | ((s_[9] & 0xFF) << 8) | ((s_[10] & 0xFF) << 16) |
                  (((unsigned)(s_[11] & 0xFF)) << 24);
    unsigned* wq = (unsigned*)(sp + tt * 192);
    wq[0] = u0; wq[1] = u1; wq[2] = u2;
  }
}

// ---------------- K2: BN1+maxpool+relu, conv2, ternarize ----
// R19: 128 threads = 2 waves/sample; thread (c2 = tid>>1, h = tid&1) computes the 4x8
// half-plane rows 4h..4h+3 (32 accs). Doubles waves/CU 8->16 (R18 was grid-limited at
// 2 waves/SIMD, 34% latency idle) while keeping low LDS traffic (8 broadcast rows per
// 800 thread-FMAs = 0.48 B/FMA) and acc-forced VGPR residency. FMA chain order per acc
// (cc, ky asc via row streaming, kx asc) and all reduction trees bit-identical
// (see emulR128).
__global__ __launch_bounds__(128, 4) void k2_conv2(
    const signed char* __restrict__ s1full, const float* __restrict__ alpha1,
    const float* __restrict__ w2t2, const float* __restrict__ b2,
    const float* __restrict__ g1, const float* __restrict__ bt1,
    signed char* __restrict__ s2full, float* __restrict__ alpha2) {
  __shared__ float pooled[4608];
  __shared__ float g1l[32], bt1l[32];
  __shared__ float red[32];

  const int tid = threadIdx.x;
  const int smp = blockIdx.x;
  const float BNINV = (float)(1.0 / sqrt(1.0 + 1e-5));

  if (tid < 32) { g1l[tid] = g1[tid] * BNINV; bt1l[tid] = bt1[tid]; }
  __syncthreads();

  const float a1 = alpha1[smp];
  for (int j = tid; j < 4608; j += 128) {
    int ci = j / 144;
    int r = j - ci * 144;
    int py = r / 12;
    int px = r - py * 12;
    const signed char* sp = s1full + (size_t)smp * 18432 + ci * 576 + py * 48 + px * 2;
    char2 t0 = *(const char2*)sp;
    char2 t1 = *(const char2*)(sp + 24);
    float m = -1e30f;
    { float v = ((float)t0.x * a1) * g1l[ci] + bt1l[ci]; m = (v > m) ? v : m; }
    { float v = ((float)t0.y * a1) * g1l[ci] + bt1l[ci]; m = (v > m) ? v : m; }
    { float v = ((float)t1.x * a1) * g1l[ci] + bt1l[ci]; m = (v > m) ? v : m; }
    { float v = ((float)t1.y * a1) * g1l[ci] + bt1l[ci]; m = (v > m) ? v : m; }
    pooled[j] = (m > 0.0f) ? m : 0.0f;
  }
  __syncthreads();

  const int c2 = tid >> 1;
  const int h = tid & 1;
  const float bias = b2[c2];
  float acc[4][8];
  #pragma unroll
  for (int r = 0; r < 4; r++)
    #pragma unroll
    for (int i = 0; i < 8; i++) acc[r][i] = bias;

  const float4* wp = ((const float4*)w2t2) + c2 * 7;  // 112 B/c2 -> 16B-aligned
  const float* pb = pooled + h * 48;                   // rows 4h..4h+7 of each plane
  #pragma unroll 1
  for (int cc = 0; cc < 32; cc++) {
    const float4 W0 = wp[0], W1 = wp[1], W2 = wp[2], W3 = wp[3],
                 W4 = wp[4], W5 = wp[5], W6 = wp[6];
    const float wk[25] = {W0.x, W0.y, W0.z, W0.w, W1.x, W1.y, W1.z, W1.w,
                          W2.x, W2.y, W2.z, W2.w, W3.x, W3.y, W3.z, W3.w,
                          W4.x, W4.y, W4.z, W4.w, W5.x, W5.y, W5.z, W5.w, W6.x};
    #pragma unroll
    for (int tt = 0; tt < 8; tt++) {
      float row[12];
      *(float4*)&row[0] = *(const float4*)&pb[tt * 12];
      *(float4*)&row[4] = *(const float4*)&pb[tt * 12 + 4];
      *(float4*)&row[8] = *(const float4*)&pb[tt * 12 + 8];
      #pragma unroll
      for (int ky = 0; ky < 5; ky++) {
        const int lr = tt - ky;          // compile-time after unroll
        if (lr >= 0 && lr < 4) {
          #pragma unroll
          for (int kx = 0; kx < 5; kx++) {
            const float w = wk[ky * 5 + kx];
            #pragma unroll
            for (int i = 0; i < 8; i++) acc[lr][i] = fmaf(row[i + kx], w, acc[lr][i]);
          }
        }
      }
    }
    wp += 448;   // next cc slab (64 c2 * 7 float4)
    pb += 144;   // next channel plane
  }

  // partials of old lanes q=2h (rows 0,1 local) and q=2h+1 (rows 2,3), old i-interleaved order.
  float as0 = 0.0f, as1 = 0.0f;
  #pragma unroll
  for (int i = 0; i < 8; i++) as0 += fabsf(acc[0][i]) + fabsf(acc[1][i]);
  #pragma unroll
  for (int i = 0; i < 8; i++) as1 += fabsf(acc[2][i]) + fabsf(acc[3][i]);
  float tot = emulR128(as0, as1, red, tid);
  float delta = (0.7f * tot) / 4096.0f;

  float ms0 = 0.0f, mc0 = 0.0f, ms1 = 0.0f, mc1 = 0.0f;
  #pragma unroll
  for (int i = 0; i < 8; i++) {
    float f0 = fabsf(acc[0][i]);
    if (f0 > delta) { ms0 += f0; mc0 += 1.0f; }
    float f1 = fabsf(acc[1][i]);
    if (f1 > delta) { ms0 += f1; mc0 += 1.0f; }
  }
  #pragma unroll
  for (int i = 0; i < 8; i++) {
    float f0 = fabsf(acc[2][i]);
    if (f0 > delta) { ms1 += f0; mc1 += 1.0f; }
    float f1 = fabsf(acc[3][i]);
    if (f1 > delta) { ms1 += f1; mc1 += 1.0f; }
  }
  float msumT = emulR128(ms0, ms1, red, tid);
  float mcntT = emulR128(mc0, mc1, red, tid);
  if (tid == 0) alpha2[smp] = (mcntT > 0.0f) ? (msumT / mcntT) : 0.0f;

  // pack signs: 2 uint4 stores covering rows (4h,4h+1) and (4h+2,4h+3) — same bytes
  // at the same addresses as the old (c2,q) threads.
  signed char* so = s2full + (size_t)smp * 4096 + c2 * 64 + h * 32;
  #pragma unroll
  for (int pr = 0; pr < 2; pr++) {
    int t_[16];
    #pragma unroll
    for (int i = 0; i < 8; i++) {
      float v = acc[2 * pr][i];
      t_[i] = (v > delta) ? 1 : ((v < -delta) ? -1 : 0);
    }
    #pragma unroll
    for (int i = 0; i < 8; i++) {
      float v = acc[2 * pr + 1][i];
      t_[8 + i] = (v > delta) ? 1 : ((v < -delta) ? -1 : 0);
    }
    unsigned u0 = (t_[0] & 0xFF) | ((t_[1] & 0xFF) << 8) | ((t_[2] & 0xFF) << 16) |
                  (((unsigned)(t_[3] & 0xFF)) << 24);
    unsigned u1 = (t_[4] & 0xFF) | ((t_[5] & 0xFF) << 8) | ((t_[6] & 0xFF) << 16) |
                  (((unsigned)(t_[7] & 0xFF)) << 24);
    unsigned u2 = (t_[8] & 0xFF) | ((t_[9] & 0xFF) << 8) | ((t_[10] & 0xFF) << 16) |
                  (((unsigned)(t_[11] & 0xFF)) << 24);
    unsigned u3 = (t_[12] & 0xFF) | ((t_[13] & 0xFF) << 8) | ((t_[14] & 0xFF) << 16) |
                  (((unsigned)(t_[15] & 0xFF)) << 24);
    *(uint4*)(so + pr * 16) = make_uint4(u0, u1, u2, u3);
  }
}

// ---------------- K0t: transpose fc1 weights into w1t[k][o] (into dead s1full) ----------
__global__ void k0_transpose(const float* __restrict__ w1f, float* __restrict__ w1t) {
  int i = blockIdx.x * 256 + threadIdx.x;  // i over 524288
  int k = i >> 9;
  int o = i & 511;
  w1t[i] = w1f[o * 1024 + k];
}

// ---------------- K3: 4 samples/block; fc1 via transposed weights ----
__global__ __launch_bounds__(1024, 4) void k3_fc(
    const signed char* __restrict__ s2full, const float* __restrict__ alpha2,
    const float* __restrict__ w1t, const float* __restrict__ f1b,
    const float* __restrict__ w2f, const float* __restrict__ f2b,
    const float* __restrict__ g2, const float* __restrict__ bt2,
    float* __restrict__ out) {
  __shared__ float S[16384];
  __shared__ float fco[4][512];
  __shared__ float g2l[64], bt2l[64];
  __shared__ float redm[4][4];
  __shared__ float out2[4][10];

  const int tid = threadIdx.x;
  const int blk = blockIdx.x;
  const float BNINV = (float)(1.0 / sqrt(1.0 + 1e-5));

  if (tid < 64) { g2l[tid] = g2[tid] * BNINV; bt2l[tid] = bt2[tid]; }
  __syncthreads();

  float* h4 = S;
  for (int e = tid; e < 4096; e += 1024) {
    int j = e >> 2;
    int s = e & 3;
    int cc = j >> 4;
    int r = j & 15;
    int py = r >> 2;
    int px = r & 3;
    const signed char* sp = s2full + (size_t)(blk * 4 + s) * 4096 + cc * 64 + (py * 2) * 8 + px * 2;
    float a2 = alpha2[blk * 4 + s];
    float m = -1e30f;
    #pragma unroll
    for (int dy = 0; dy < 2; dy++)
      #pragma unroll
      for (int dx = 0; dx < 2; dx++) {
        float v = ((float)sp[dy * 8 + dx] * a2) * g2l[cc] + bt2l[cc];
        m = (v > m) ? v : m;
      }
    h4[j * 4 + s] = (m > 0.0f) ? m : 0.0f;
  }
  __syncthreads();

  const int kp = tid >> 7;
  const int og = tid & 127;
  float a00=0,a01=0,a02=0,a03=0, a10=0,a11=0,a12=0,a13=0;
  float a20=0,a21=0,a22=0,a23=0, a30=0,a31=0,a32=0,a33=0;
  const float4* w4 = (const float4*)w1t;
  const float4* h44 = (const float4*)h4;
  const int kbase = kp << 7;
  for (int kk = 0; kk < 128; kk++) {
    const int k = kbase + kk;
    const float4 wv = w4[(k << 7) + og];
    const float4 hv = h44[k];
    a00 = fmaf(hv.x, wv.x, a00); a01 = fmaf(hv.y, wv.x, a01);
    a02 = fmaf(hv.z, wv.x, a02); a03 = fmaf(hv.w, wv.x, a03);
    a10 = fmaf(hv.x, wv.y, a10); a11 = fmaf(hv.y, wv.y, a11);
    a12 = fmaf(hv.z, wv.y, a12); a13 = fmaf(hv.w, wv.y, a13);
    a20 = fmaf(hv.x, wv.z, a20); a21 = fmaf(hv.y, wv.z, a21);
    a22 = fmaf(hv.z, wv.z, a22); a23 = fmaf(hv.w, wv.z, a23);
    a30 = fmaf(hv.x, wv.w, a30); a31 = fmaf(hv.y, wv.w, a31);
    a32 = fmaf(hv.z, wv.w, a32); a33 = fmaf(hv.w, wv.w, a33);
  }
  __syncthreads();
  {
    float4* p4 = (float4*)S;
    const int base = (kp << 9) + (og << 2);
    p4[base + 0] = make_float4(a00, a01, a02, a03);
    p4[base + 1] = make_float4(a10, a11, a12, a13);
    p4[base + 2] = make_float4(a20, a21, a22, a23);
    p4[base + 3] = make_float4(a30, a31, a32, a33);
  }
  __syncthreads();

  for (int p = tid; p < 2048; p += 1024) {
    int o = p >> 2;
    int s = p & 3;
    float v = S[p];
    #pragma unroll
    for (int kp2 = 1; kp2 < 8; kp2++) v += S[kp2 * 2048 + p];
    fco[s][o] = v + f1b[o];
  }
  __syncthreads();

  float (*h3)[512] = (float(*)[512])S;
  const int sg = tid >> 8;
  const int tj = tid & 255;
  float v0 = fco[sg][tj];
  float v1 = fco[sg][tj + 256];
  float av0 = fabsf(v0), av1 = fabsf(v1);
  float tot = groupReduce4w(av0 + av1, redm[sg], tj);
  float delta = (0.7f * tot) / 512.0f;
  float m0 = (av0 > delta) ? av0 : 0.0f;
  float m1 = (av1 > delta) ? av1 : 0.0f;
  float msum = groupReduce4w(m0 + m1, redm[sg], tj);
  float mcnt = groupReduce4w(((av0 > delta) ? 1.0f : 0.0f) + ((av1 > delta) ? 1.0f : 0.0f),
                             redm[sg], tj);
  float alpha3 = (mcnt > 0.0f) ? (msum / mcnt) : 0.0f;
  {
    float t0 = (v0 > delta) ? 1.0f : ((v0 < -delta) ? -1.0f : 0.0f);
    float hv0 = t0 * alpha3;
    h3[sg][tj] = (hv0 > 0.0f) ? hv0 : 0.0f;
    float t1 = (v1 > delta) ? 1.0f : ((v1 < -delta) ? -1.0f : 0.0f);
    float hv1 = t1 * alpha3;
    h3[sg][tj + 256] = (hv1 > 0.0f) ? hv1 : 0.0f;
  }
  __syncthreads();

  const int lane = tid & 63;
  const int wid = tid >> 6;
  for (int t = wid; t < 40; t += 16) {
    int s = t / 10;
    int o = t - s * 10;
    float acc = 0.0f;
    #pragma unroll
    for (int m = 0; m < 8; m++) {
      int j = lane + (m << 6);
      acc = fmaf(h3[s][j], w2f[o * 512 + j], acc);
    }
    #pragma unroll
    for (int off = 32; off > 0; off >>= 1) acc += __shfl_xor(acc, off);
    if (lane == 0) out2[s][o] = acc + f2b[o];
  }
  __syncthreads();

  if (tid < 4) {
    int s = tid;
    float t2 = 0.0f;
    for (int i = 0; i < 10; i++) t2 += fabsf(out2[s][i]);
    float d = (0.7f * t2) / 10.0f;
    float ms = 0.0f, mc = 0.0f;
    for (int i = 0; i < 10; i++) {
      float a = fabsf(out2[s][i]);
      if (a > d) { ms += a; mc += 1.0f; }
    }
    float al = (mc > 0.0f) ? (ms / mc) : 0.0f;
    for (int i = 0; i < 10; i++) {
      float vv = out2[s][i];
      float sv = (vv > d) ? 1.0f : ((vv < -d) ? -1.0f : 0.0f);
      out[(size_t)(blk * 4 + s) * 10 + i] = sv * al;
    }
  }
}

// assumption-violation marker
__global__ void k_marker(float* __restrict__ out, int n, float val) {
  int i = blockIdx.x * 256 + threadIdx.x;
  if (i < n) out[i] = val;
}

extern "C" void kernel_launch(void* const* d_in, const int* in_sizes, int n_in,
                              void* d_out, int out_size, void* d_ws, size_t ws_size,
                              hipStream_t stream) {
  float* out = (float*)d_out;

  static const int expect[13] = {1605632, 800, 32, 32, 32, 51200, 64, 64, 64,
                                 524288, 512, 5120, 10};
  float marker = 0.0f;
  if (n_in != 13) marker = 304.0f;
  else {
    for (int i = 0; i < 13; i++)
      if (in_sizes[i] != expect[i]) { marker = 320.0f + 16.0f * i; break; }
  }
  if (marker == 0.0f && out_size != 20480) marker = 560.0f;

  float* alpha1 = (float*)d_ws;                           // 2048
  float* alpha2 = alpha1 + BATCH;                         // 2048
  float* w2t2   = alpha2 + BATCH;                         // 57344 (229 KB, padded)
  signed char* s1full = (signed char*)(w2t2 + 57344);     // 2048*18432 (dead after k2;
                                                          //  first 2MB reused as w1t)
  signed char* s2full = s1full + (size_t)BATCH * 18432;   // 2048*4096
  size_t needed = (size_t)((s2full + (size_t)BATCH * 4096) - (signed char*)d_ws);
  if (marker == 0.0f && ws_size < needed) marker = 576.0f;

  if (marker != 0.0f) {
    k_marker<<<dim3((out_size + 255) / 256), dim3(256), 0, stream>>>(out, out_size, marker);
    return;
  }

  const float* x   = (const float*)d_in[0];
  const float* c1w = (const float*)d_in[1];
  const float* c1b = (const float*)d_in[2];
  const float* g1  = (const float*)d_in[3];
  const float* bt1 = (const float*)d_in[4];
  const float* c2w = (const float*)d_in[5];
  const float* c2b = (const float*)d_in[6];
  const float* g2  = (const float*)d_in[7];
  const float* bt2 = (const float*)d_in[8];
  const float* f1w = (const float*)d_in[9];
  const float* f1b = (const float*)d_in[10];
  const float* f2w = (const float*)d_in[11];
  const float* f2b = (const float*)d_in[12];

  float* w1t = (float*)s1full;

  k0_w2t<<<dim3(224), dim3(256), 0, stream>>>(c2w, w2t2);
  k1_conv1<<<dim3(BATCH), dim3(512), 0, stream>>>(x, c1w, c1b, s1full, alpha1);
  k2_conv2<<<dim3(BATCH), dim3(128), 0, stream>>>(s1full, alpha1, w2t2, c2b, g1, bt1, s2full, alpha2);
  k0_transpose<<<dim3(2048), dim3(256), 0, stream>>>(f1w, w1t);
  k3_fc<<<dim3(BATCH / 4), dim3(1024), 0, stream>>>(s2full, alpha2, w1t, f1b, f2w, f2b, g2, bt2, out);
}